// Round 7
// baseline (329.084 us; speedup 1.0000x reference)
//
#include <hip/hip_runtime.h>
#include <stdint.h>

typedef __attribute__((ext_vector_type(8))) __bf16 bf16x8;
typedef __attribute__((ext_vector_type(4))) float f32x4;
typedef __attribute__((ext_vector_type(8))) unsigned short ushort8;

#define T_TOK 2048
#define D_DIM 1024
#define DFF   2816
#define NEXP  8
#define NROWS 4096
#define BK    32
#define NW_ELEM (NEXP * DFF * D_DIM)   // 23,068,672 elems per weight tensor

// granule swizzle for bf16 tiles (4 x 16B granules per 64B row); involution.
#define SWZ(r,g) ((g) ^ (((r) >> 1) & 3))

// ---------- helpers ----------
__device__ __forceinline__ void lds_cp16(const void* g, void* l) {
  __builtin_amdgcn_global_load_lds(
      (const __attribute__((address_space(1))) void*)g,
      (__attribute__((address_space(3))) void*)l, 16, 0, 0);
}

__device__ __forceinline__ ushort8 pack_bf16x8(float4 a, float4 b) {
  union { __bf16 h[8]; ushort8 u; } r;
  r.h[0] = (__bf16)a.x; r.h[1] = (__bf16)a.y; r.h[2] = (__bf16)a.z; r.h[3] = (__bf16)a.w;
  r.h[4] = (__bf16)b.x; r.h[5] = (__bf16)b.y; r.h[6] = (__bf16)b.z; r.h[7] = (__bf16)b.w;
  return r.u;
}

__device__ __forceinline__ unsigned short f2bf(float f) {
  union { __bf16 h; unsigned short u; } r;
  r.h = (__bf16)f;
  return r.u;
}

// ---------- 1. routing ----------
__global__ __launch_bounds__(512) void routing_kernel(
    const int* __restrict__ ids, const float* __restrict__ w,
    int* __restrict__ cnt, int* __restrict__ off,
    int* __restrict__ tok, float* __restrict__ wgt, int* __restrict__ rowmap)
{
  __shared__ int s_cnt[NEXP];
  __shared__ int s_off[NEXP];
  const int lane = threadIdx.x & 63;
  const int e    = threadIdx.x >> 6;

  int total = 0;
  for (int c = 0; c < NROWS / 64; ++c) {
    int id = ids[c * 64 + lane];
    unsigned long long b = __ballot(id == e);
    total += __popcll(b);
  }
  if (lane == 0) s_cnt[e] = total;
  __syncthreads();
  if (threadIdx.x == 0) {
    int acc = 0;
    for (int i = 0; i < NEXP; ++i) {
      s_off[i] = acc; off[i] = acc; cnt[i] = s_cnt[i]; acc += s_cnt[i];
    }
  }
  __syncthreads();
  int base = s_off[e];
  for (int c = 0; c < NROWS / 64; ++c) {
    int idx = c * 64 + lane;
    int id = ids[idx];
    bool m = (id == e);
    unsigned long long b = __ballot(m);
    int pos = __popcll(b & ((1ull << lane) - 1ull));
    if (m) {
      tok[base + pos] = idx >> 1;
      wgt[base + pos] = w[idx];
      rowmap[idx] = base + pos;
    }
    base += __popcll(b);
  }
}

// ---------- 2. gather x -> bf16 compacted ----------
__global__ __launch_bounds__(256) void gather_x_kernel(
    const float* __restrict__ x, const int* __restrict__ tok,
    unsigned short* __restrict__ xg)
{
  const int i = blockIdx.x;
  const int t = tok[i];
  const float4 v = ((const float4*)(x + (size_t)t * D_DIM))[threadIdx.x];
  ushort4 o;
  o.x = f2bf(v.x); o.y = f2bf(v.y); o.z = f2bf(v.z); o.w = f2bf(v.w);
  ((ushort4*)(xg + (size_t)i * D_DIM))[threadIdx.x] = o;
}

// ---------- 2b. weight conversion f32 -> bf16 (streaming, HBM-bound) ----------
#define WCONV_CHUNKS (3 * NW_ELEM / 8)   // 8,650,752 chunks of 8 elems

__global__ __launch_bounds__(256) void wconv_kernel(
    const float* __restrict__ gw, const float* __restrict__ uw,
    const float* __restrict__ dw,
    unsigned short* __restrict__ gb, unsigned short* __restrict__ ub,
    unsigned short* __restrict__ db)
{
  const int stride = gridDim.x * blockDim.x;
  for (size_t i = (size_t)blockIdx.x * blockDim.x + threadIdx.x;
       i < WCONV_CHUNKS; i += stride) {
    size_t seg = i / (NW_ELEM / 8);
    size_t idx = (i - seg * (NW_ELEM / 8)) * 8;
    const float* src = (seg == 0) ? gw : (seg == 1) ? uw : dw;
    unsigned short* dst = (seg == 0) ? gb : (seg == 1) ? ub : db;
    float4 a = *(const float4*)(src + idx);
    float4 b = *(const float4*)(src + idx + 4);
    *(ushort8*)(dst + idx) = pack_bf16x8(a, b);
  }
}

// ---------- 3. grouped GEMM (all-bf16, full-DMA, 2ph): h = silu(x gT)*(x uT)*w ----------
#define BM_A 128
#define BN_A 64
#define NT_A (DFF / BN_A)       // 44
#define MT_A (NROWS / BM_A)     // 32
#define NWG_A (NT_A * MT_A * NEXP)  // 11264
#define KT_A (D_DIM / BK)       // 32

__global__ __launch_bounds__(256) void moe_gateup_bf(
    const unsigned short* __restrict__ gbuf, const unsigned short* __restrict__ ubuf,
    const unsigned short* __restrict__ xg, const float* __restrict__ wgt,
    const int* __restrict__ cnt, const int* __restrict__ off,
    unsigned short* __restrict__ hbuf)
{
  const int orig = blockIdx.x;
  const int wgid = (orig & 7) * (NWG_A >> 3) + (orig >> 3);
  const int mt = wgid % MT_A;
  const int t1 = wgid / MT_A;
  const int nt = t1 % NT_A;
  const int e  = t1 / NT_A;

  const int cnte = cnt[e];
  const int m0 = mt * BM_A;
  if (m0 >= cnte) return;
  const int row_base = off[e] + m0;
  const int valid = min(BM_A, cnte - m0);
  const int n0 = nt * BN_A;

  __shared__ __align__(16) unsigned short Alds[2][BM_A * BK]; // 2 x 8KB
  __shared__ __align__(16) unsigned short Bg[2][BN_A * BK];   // 2 x 4KB
  __shared__ __align__(16) unsigned short Bu[2][BN_A * BK];   // 2 x 4KB

  const int tid = threadIdx.x;
  const int lane = tid & 63;
  const int wid = tid >> 6;
  const int wm = wid >> 1, wn = wid & 1;   // wave subtile 64x32
  const int lhi = lane >> 4, llo = lane & 15;

  f32x4 accg[4][2], accu[4][2];
  #pragma unroll
  for (int i = 0; i < 4; ++i)
    #pragma unroll
    for (int j = 0; j < 2; ++j) {
      accg[i][j] = (f32x4){0.f, 0.f, 0.f, 0.f};
      accu[i][j] = (f32x4){0.f, 0.f, 0.f, 0.f};
    }

  const unsigned short* gb = gbuf + ((size_t)e * DFF + n0) * D_DIM;
  const unsigned short* ub = ubuf + ((size_t)e * DFF + n0) * D_DIM;

  const int ar0 = tid >> 2,          ag0 = tid & 3;
  const int ar1 = (tid + 256) >> 2,  ag1 = tid & 3;
  const size_t a_src0 = (size_t)(row_base + min(ar0, valid - 1)) * D_DIM + SWZ(ar0, ag0) * 8;
  const size_t a_src1 = (size_t)(row_base + min(ar1, valid - 1)) * D_DIM + SWZ(ar1, ag1) * 8;
  const int br = tid >> 2, bg = tid & 3;
  const size_t b_src = (size_t)br * D_DIM + SWZ(br, bg) * 8;

  // prologue: stage tile 0 entirely via DMA
  lds_cp16(xg + a_src0, &Alds[0][tid * 8]);
  lds_cp16(xg + a_src1, &Alds[0][(tid + 256) * 8]);
  lds_cp16(gb + b_src, &Bg[0][tid * 8]);
  lds_cp16(ub + b_src, &Bu[0][tid * 8]);
  __syncthreads();

  for (int t = 0; t < KT_A; ++t) {
    const int cur = t & 1, nxt = cur ^ 1;
    const int kn = (t + 1 < KT_A) ? (t + 1) * BK : 0;

    lds_cp16(xg + a_src0 + kn, &Alds[nxt][tid * 8]);
    lds_cp16(xg + a_src1 + kn, &Alds[nxt][(tid + 256) * 8]);
    lds_cp16(gb + b_src + kn, &Bg[nxt][tid * 8]);
    lds_cp16(ub + b_src + kn, &Bu[nxt][tid * 8]);

    bf16x8 a[4], bgf[2], buf_[2];
    #pragma unroll
    for (int mi = 0; mi < 4; ++mi) {
      int row = wm * 64 + mi * 16 + llo;
      a[mi] = *(const bf16x8*)&Alds[cur][row * BK + SWZ(row, lhi) * 8];
    }
    #pragma unroll
    for (int ni = 0; ni < 2; ++ni) {
      int row = wn * 32 + ni * 16 + llo;
      bgf[ni]  = *(const bf16x8*)&Bg[cur][row * BK + SWZ(row, lhi) * 8];
      buf_[ni] = *(const bf16x8*)&Bu[cur][row * BK + SWZ(row, lhi) * 8];
    }
    #pragma unroll
    for (int mi = 0; mi < 4; ++mi)
      #pragma unroll
      for (int ni = 0; ni < 2; ++ni) {
        accg[mi][ni] = __builtin_amdgcn_mfma_f32_16x16x32_bf16(a[mi], bgf[ni], accg[mi][ni], 0, 0, 0);
        accu[mi][ni] = __builtin_amdgcn_mfma_f32_16x16x32_bf16(a[mi], buf_[ni], accu[mi][ni], 0, 0, 0);
      }
    __syncthreads();
  }

  // epilogue: h = silu(g)*u*w -> bf16
  #pragma unroll
  for (int mi = 0; mi < 4; ++mi) {
    #pragma unroll
    for (int r = 0; r < 4; ++r) {
      int row = wm * 64 + mi * 16 + lhi * 4 + r;
      if (row < valid) {
        int grow = row_base + row;
        float wv = wgt[grow];
        size_t base = (size_t)grow * DFF + n0 + wn * 32;
        #pragma unroll
        for (int ni = 0; ni < 2; ++ni) {
          float g = accg[mi][ni][r];
          float u = accu[mi][ni][r];
          float h = (g / (1.f + __expf(-g))) * u * wv;
          hbuf[base + ni * 16 + llo] = f2bf(h);
        }
      }
    }
  }
}

// ---------- 4. grouped GEMM (all-bf16, full-DMA, split-K): y = h downT ----------
#define BM_B 128
#define BN_B 128
#define NT_B (D_DIM / BN_B)     // 8
#define MT_B (NROWS / BM_B)     // 32
#define SLICES_B 4

template <bool USE_YBUF>
__global__ __launch_bounds__(256) void moe_down_bf(
    const unsigned short* __restrict__ dbuf,
    const unsigned short* __restrict__ hbuf,
    const int* __restrict__ tok,
    const int* __restrict__ cnt, const int* __restrict__ off,
    float* __restrict__ ybuf_or_out)
{
  constexpr int KS = DFF / SLICES_B;   // 704
  constexpr int KT = KS / BK;          // 22
  constexpr int NWG = NT_B * MT_B * NEXP * SLICES_B;  // 8192

  const int orig = blockIdx.x;
  const int wgid = (orig & 7) * (NWG >> 3) + (orig >> 3);
  const int mt = wgid % MT_B;
  const int t1 = wgid / MT_B;
  const int nt = t1 % NT_B;
  const int t2 = t1 / NT_B;
  const int e  = t2 % NEXP;
  const int sl = t2 / NEXP;

  const int cnte = cnt[e];
  const int m0 = mt * BM_B;
  if (m0 >= cnte) return;
  const int row_base = off[e] + m0;
  const int valid = min(BM_B, cnte - m0);
  const int n0 = nt * BN_B;
  const int kbeg = sl * KS;

  __shared__ __align__(16) unsigned short Alds[2][BM_B * BK]; // 2 x 8KB
  __shared__ __align__(16) unsigned short Blds[2][BN_B * BK]; // 2 x 8KB

  const int tid = threadIdx.x, lane = tid & 63, wid = tid >> 6;
  const int wm = wid >> 1, wn = wid & 1;   // wave subtile 64x64
  const int lhi = lane >> 4, llo = lane & 15;

  f32x4 acc[4][4];
  #pragma unroll
  for (int i = 0; i < 4; ++i)
    #pragma unroll
    for (int j = 0; j < 4; ++j) acc[i][j] = (f32x4){0.f, 0.f, 0.f, 0.f};

  const unsigned short* db = dbuf + ((size_t)e * D_DIM + n0) * DFF;

  const int ar0 = tid >> 2,          ag0 = tid & 3;
  const int ar1 = (tid + 256) >> 2,  ag1 = tid & 3;
  const size_t a_src0 = (size_t)(row_base + min(ar0, valid - 1)) * DFF + SWZ(ar0, ag0) * 8;
  const size_t a_src1 = (size_t)(row_base + min(ar1, valid - 1)) * DFF + SWZ(ar1, ag1) * 8;
  const size_t b_src0 = (size_t)ar0 * DFF + SWZ(ar0, ag0) * 8;
  const size_t b_src1 = (size_t)ar1 * DFF + SWZ(ar1, ag1) * 8;

  lds_cp16(hbuf + a_src0 + kbeg, &Alds[0][tid * 8]);
  lds_cp16(hbuf + a_src1 + kbeg, &Alds[0][(tid + 256) * 8]);
  lds_cp16(db + b_src0 + kbeg, &Blds[0][tid * 8]);
  lds_cp16(db + b_src1 + kbeg, &Blds[0][(tid + 256) * 8]);
  __syncthreads();

  for (int t = 0; t < KT; ++t) {
    const int cur = t & 1, nxt = cur ^ 1;
    const int kn = kbeg + ((t + 1 < KT) ? (t + 1) * BK : 0);

    lds_cp16(hbuf + a_src0 + kn, &Alds[nxt][tid * 8]);
    lds_cp16(hbuf + a_src1 + kn, &Alds[nxt][(tid + 256) * 8]);
    lds_cp16(db + b_src0 + kn, &Blds[nxt][tid * 8]);
    lds_cp16(db + b_src1 + kn, &Blds[nxt][(tid + 256) * 8]);

    bf16x8 a[4], b[4];
    #pragma unroll
    for (int mi = 0; mi < 4; ++mi) {
      int row = wm * 64 + mi * 16 + llo;
      a[mi] = *(const bf16x8*)&Alds[cur][row * BK + SWZ(row, lhi) * 8];
    }
    #pragma unroll
    for (int ni = 0; ni < 4; ++ni) {
      int row = wn * 64 + ni * 16 + llo;
      b[ni] = *(const bf16x8*)&Blds[cur][row * BK + SWZ(row, lhi) * 8];
    }
    #pragma unroll
    for (int mi = 0; mi < 4; ++mi)
      #pragma unroll
      for (int ni = 0; ni < 4; ++ni)
        acc[mi][ni] = __builtin_amdgcn_mfma_f32_16x16x32_bf16(a[mi], b[ni], acc[mi][ni], 0, 0, 0);
    __syncthreads();
  }

  #pragma unroll
  for (int mi = 0; mi < 4; ++mi) {
    #pragma unroll
    for (int r = 0; r < 4; ++r) {
      int row = wm * 64 + mi * 16 + lhi * 4 + r;
      if (row < valid) {
        if (USE_YBUF) {
          float* yp = ybuf_or_out + ((size_t)sl * NROWS + row_base + row) * D_DIM + n0 + wn * 64;
          #pragma unroll
          for (int ni = 0; ni < 4; ++ni) yp[ni * 16 + llo] = acc[mi][ni][r];
        } else {
          int tk = tok[row_base + row];
          float* op = ybuf_or_out + (size_t)tk * D_DIM + n0 + wn * 64;
          #pragma unroll
          for (int ni = 0; ni < 4; ++ni) atomicAdd(op + ni * 16 + llo, acc[mi][ni][r]);
        }
      }
    }
  }
}

// ---------- fallback (round-6 path, f32 B reg-staged): gateup + atomic down ----------
__global__ __launch_bounds__(256) void moe_gateup_f32(
    const float* __restrict__ gate_w, const float* __restrict__ up_w,
    const unsigned short* __restrict__ xg, const float* __restrict__ wgt,
    const int* __restrict__ cnt, const int* __restrict__ off,
    unsigned short* __restrict__ hbuf)
{
  const int orig = blockIdx.x;
  const int wgid = (orig & 7) * (NWG_A >> 3) + (orig >> 3);
  const int mt = wgid % MT_A;
  const int t1 = wgid / MT_A;
  const int nt = t1 % NT_A;
  const int e  = t1 / NT_A;

  const int cnte = cnt[e];
  const int m0 = mt * BM_A;
  if (m0 >= cnte) return;
  const int row_base = off[e] + m0;
  const int valid = min(BM_A, cnte - m0);
  const int n0 = nt * BN_A;

  __shared__ __align__(16) unsigned short Alds[2][BM_A * BK];
  __shared__ __align__(16) unsigned short Bg[2][BN_A * BK];
  __shared__ __align__(16) unsigned short Bu[2][BN_A * BK];

  const int tid = threadIdx.x;
  const int lane = tid & 63;
  const int wid = tid >> 6;
  const int wm = wid >> 1, wn = wid & 1;
  const int lhi = lane >> 4, llo = lane & 15;

  f32x4 accg[4][2], accu[4][2];
  #pragma unroll
  for (int i = 0; i < 4; ++i)
    #pragma unroll
    for (int j = 0; j < 2; ++j) {
      accg[i][j] = (f32x4){0.f, 0.f, 0.f, 0.f};
      accu[i][j] = (f32x4){0.f, 0.f, 0.f, 0.f};
    }

  const float* gbase = gate_w + ((size_t)e * DFF + n0) * D_DIM;
  const float* ubase = up_w   + ((size_t)e * DFF + n0) * D_DIM;
  const int rowb = tid >> 2;
  const int gidx = tid & 3;

  const int ar0 = tid >> 2,          ag0 = tid & 3;
  const int ar1 = (tid + 256) >> 2,  ag1 = tid & 3;
  const size_t a_src0 = (size_t)(row_base + min(ar0, valid - 1)) * D_DIM + SWZ(ar0, ag0) * 8;
  const size_t a_src1 = (size_t)(row_base + min(ar1, valid - 1)) * D_DIM + SWZ(ar1, ag1) * 8;
  const size_t boff  = (size_t)rowb * D_DIM + gidx * 8;
  const int bws = rowb * BK + SWZ(rowb, gidx) * 8;

  lds_cp16(xg + a_src0, &Alds[0][tid * 8]);
  lds_cp16(xg + a_src1, &Alds[0][(tid + 256) * 8]);
  {
    const float* gp = gbase + boff;
    const float* up = ubase + boff;
    *(ushort8*)&Bg[0][bws] = pack_bf16x8(*(const float4*)gp, *(const float4*)(gp + 4));
    *(ushort8*)&Bu[0][bws] = pack_bf16x8(*(const float4*)up, *(const float4*)(up + 4));
  }
  float4 pg0, pg1, pu0, pu1;
  {
    const float* gp = gbase + boff + BK;
    const float* up = ubase + boff + BK;
    pg0 = *(const float4*)gp; pg1 = *(const float4*)(gp + 4);
    pu0 = *(const float4*)up; pu1 = *(const float4*)(up + 4);
  }
  __syncthreads();

  for (int t = 0; t < KT_A; ++t) {
    const int cur = t & 1, nxt = cur ^ 1;
    const int kn1 = (t + 1 < KT_A) ? (t + 1) * BK : 0;
    const int kn2 = (t + 2 < KT_A) ? (t + 2) * BK : 0;

    lds_cp16(xg + a_src0 + kn1, &Alds[nxt][tid * 8]);
    lds_cp16(xg + a_src1 + kn1, &Alds[nxt][(tid + 256) * 8]);
    const float* gp = gbase + boff + kn2;
    const float* up = ubase + boff + kn2;
    float4 ng0 = *(const float4*)gp, ng1 = *(const float4*)(gp + 4);
    float4 nu0 = *(const float4*)up, nu1 = *(const float4*)(up + 4);
    *(ushort8*)&Bg[nxt][bws] = pack_bf16x8(pg0, pg1);
    *(ushort8*)&Bu[nxt][bws] = pack_bf16x8(pu0, pu1);

    bf16x8 a[4], bgf[2], buf_[2];
    #pragma unroll
    for (int mi = 0; mi < 4; ++mi) {
      int row = wm * 64 + mi * 16 + llo;
      a[mi] = *(const bf16x8*)&Alds[cur][row * BK + SWZ(row, lhi) * 8];
    }
    #pragma unroll
    for (int ni = 0; ni < 2; ++ni) {
      int row = wn * 32 + ni * 16 + llo;
      bgf[ni]  = *(const bf16x8*)&Bg[cur][row * BK + SWZ(row, lhi) * 8];
      buf_[ni] = *(const bf16x8*)&Bu[cur][row * BK + SWZ(row, lhi) * 8];
    }
    #pragma unroll
    for (int mi = 0; mi < 4; ++mi)
      #pragma unroll
      for (int ni = 0; ni < 2; ++ni) {
        accg[mi][ni] = __builtin_amdgcn_mfma_f32_16x16x32_bf16(a[mi], bgf[ni], accg[mi][ni], 0, 0, 0);
        accu[mi][ni] = __builtin_amdgcn_mfma_f32_16x16x32_bf16(a[mi], buf_[ni], accu[mi][ni], 0, 0, 0);
      }

    pg0 = ng0; pg1 = ng1; pu0 = nu0; pu1 = nu1;
    __syncthreads();
  }

  #pragma unroll
  for (int mi = 0; mi < 4; ++mi) {
    #pragma unroll
    for (int r = 0; r < 4; ++r) {
      int row = wm * 64 + mi * 16 + lhi * 4 + r;
      if (row < valid) {
        int grow = row_base + row;
        float wv = wgt[grow];
        size_t base = (size_t)grow * DFF + n0 + wn * 32;
        #pragma unroll
        for (int ni = 0; ni < 2; ++ni) {
          float g = accg[mi][ni][r];
          float u = accu[mi][ni][r];
          float h = (g / (1.f + __expf(-g))) * u * wv;
          hbuf[base + ni * 16 + llo] = f2bf(h);
        }
      }
    }
  }
}

__global__ __launch_bounds__(256) void moe_down_f32(
    const float* __restrict__ down_w,
    const unsigned short* __restrict__ hbuf,
    const int* __restrict__ tok,
    const int* __restrict__ cnt, const int* __restrict__ off,
    float* __restrict__ out)
{
  constexpr int SLICES = 2;
  constexpr int KS = DFF / SLICES;
  constexpr int KT = KS / BK;
  constexpr int BMf = 128, BNf = 64;
  constexpr int NTf = D_DIM / BNf, MTf = NROWS / BMf;
  constexpr int NWG = NTf * MTf * NEXP * SLICES;

  const int orig = blockIdx.x;
  const int wgid = (orig & 7) * (NWG >> 3) + (orig >> 3);
  const int mt = wgid % MTf;
  const int t1 = wgid / MTf;
  const int nt = t1 % NTf;
  const int t2 = t1 / NTf;
  const int e  = t2 % NEXP;
  const int sl = t2 / NEXP;

  const int cnte = cnt[e];
  const int m0 = mt * BMf;
  if (m0 >= cnte) return;
  const int row_base = off[e] + m0;
  const int valid = min(BMf, cnte - m0);
  const int n0 = nt * BNf;
  const int kbeg = sl * KS;

  __shared__ __align__(16) unsigned short Alds[2][BMf * BK];
  __shared__ __align__(16) unsigned short Blds[2][BNf * BK];

  const int tid = threadIdx.x, lane = tid & 63, wid = tid >> 6;
  const int wm = wid >> 1, wn = wid & 1;
  const int lhi = lane >> 4, llo = lane & 15;

  f32x4 acc[4][2];
  #pragma unroll
  for (int i = 0; i < 4; ++i)
    #pragma unroll
    for (int j = 0; j < 2; ++j) acc[i][j] = (f32x4){0.f, 0.f, 0.f, 0.f};

  const float* dbase = down_w + ((size_t)e * D_DIM + n0) * DFF;
  const int rowb = tid >> 2, gidx = tid & 3;
  const int ar0 = tid >> 2,          ag0 = tid & 3;
  const int ar1 = (tid + 256) >> 2,  ag1 = tid & 3;
  const size_t a_src0 = (size_t)(row_base + min(ar0, valid - 1)) * DFF + SWZ(ar0, ag0) * 8;
  const size_t a_src1 = (size_t)(row_base + min(ar1, valid - 1)) * DFF + SWZ(ar1, ag1) * 8;
  const size_t boff  = (size_t)rowb * DFF + gidx * 8;
  const int bws = rowb * BK + SWZ(rowb, gidx) * 8;

  lds_cp16(hbuf + a_src0 + kbeg, &Alds[0][tid * 8]);
  lds_cp16(hbuf + a_src1 + kbeg, &Alds[0][(tid + 256) * 8]);
  {
    const float* dp = dbase + boff + kbeg;
    *(ushort8*)&Blds[0][bws] = pack_bf16x8(*(const float4*)dp, *(const float4*)(dp + 4));
  }
  float4 pd0, pd1;
  {
    const float* dp = dbase + boff + kbeg + BK;
    pd0 = *(const float4*)dp; pd1 = *(const float4*)(dp + 4);
  }
  __syncthreads();

  for (int t = 0; t < KT; ++t) {
    const int cur = t & 1, nxt = cur ^ 1;
    const int kn1 = kbeg + ((t + 1 < KT) ? (t + 1) * BK : 0);
    const int kn2 = kbeg + ((t + 2 < KT) ? (t + 2) * BK : 0);

    lds_cp16(hbuf + a_src0 + kn1, &Alds[nxt][tid * 8]);
    lds_cp16(hbuf + a_src1 + kn1, &Alds[nxt][(tid + 256) * 8]);
    const float* dp = dbase + boff + kn2;
    float4 nd0 = *(const float4*)dp, nd1 = *(const float4*)(dp + 4);
    *(ushort8*)&Blds[nxt][bws] = pack_bf16x8(pd0, pd1);

    bf16x8 a[4], b[2];
    #pragma unroll
    for (int mi = 0; mi < 4; ++mi) {
      int row = wm * 64 + mi * 16 + llo;
      a[mi] = *(const bf16x8*)&Alds[cur][row * BK + SWZ(row, lhi) * 8];
    }
    #pragma unroll
    for (int ni = 0; ni < 2; ++ni) {
      int row = wn * 32 + ni * 16 + llo;
      b[ni] = *(const bf16x8*)&Blds[cur][row * BK + SWZ(row, lhi) * 8];
    }
    #pragma unroll
    for (int mi = 0; mi < 4; ++mi)
      #pragma unroll
      for (int ni = 0; ni < 2; ++ni)
        acc[mi][ni] = __builtin_amdgcn_mfma_f32_16x16x32_bf16(a[mi], b[ni], acc[mi][ni], 0, 0, 0);

    pd0 = nd0; pd1 = nd1;
    __syncthreads();
  }

  #pragma unroll
  for (int mi = 0; mi < 4; ++mi) {
    #pragma unroll
    for (int r = 0; r < 4; ++r) {
      int row = wm * 64 + mi * 16 + lhi * 4 + r;
      if (row < valid) {
        int tk = tok[row_base + row];
        float* op = out + (size_t)tk * D_DIM + n0 + wn * 32;
        #pragma unroll
        for (int ni = 0; ni < 2; ++ni) atomicAdd(op + ni * 16 + llo, acc[mi][ni][r]);
      }
    }
  }
}

// ---------- 5. combine ----------
__global__ __launch_bounds__(256) void combine_kernel(
    const float* __restrict__ ybuf, const int* __restrict__ rowmap,
    float* __restrict__ out)
{
  const int t = blockIdx.x;
  const int d = threadIdx.x * 4;
  const int r0 = rowmap[t * 2], r1 = rowmap[t * 2 + 1];
  float4 s = {0.f, 0.f, 0.f, 0.f};
  #pragma unroll
  for (int sl = 0; sl < SLICES_B; ++sl) {
    const float4 a = *(const float4*)(ybuf + ((size_t)sl * NROWS + r0) * D_DIM + d);
    const float4 b = *(const float4*)(ybuf + ((size_t)sl * NROWS + r1) * D_DIM + d);
    s.x += a.x + b.x; s.y += a.y + b.y; s.z += a.z + b.z; s.w += a.w + b.w;
  }
  *(float4*)(out + (size_t)t * D_DIM + d) = s;
}

// ---------- launch ----------
extern "C" void kernel_launch(void* const* d_in, const int* in_sizes, int n_in,
                              void* d_out, int out_size, void* d_ws, size_t ws_size,
                              hipStream_t stream) {
  const float* x      = (const float*)d_in[0];
  const float* topk_w = (const float*)d_in[1];
  const float* gate_w = (const float*)d_in[2];
  const float* up_w   = (const float*)d_in[3];
  const float* down_w = (const float*)d_in[4];
  const int*   ids    = (const int*)d_in[5];
  float* out = (float*)d_out;

  char* ws = (char*)d_ws;
  int*   cnt    = (int*)(ws + 0);
  int*   off    = (int*)(ws + 32);
  int*   tok    = (int*)(ws + 64);
  float* wgt    = (float*)(ws + 64 + NROWS * 4);
  int*   rowmap = (int*)(ws + 64 + NROWS * 8);

  const size_t XG_OFF   = 65536;
  const size_t XG_SZ    = (size_t)NROWS * D_DIM * 2;            // 8 MB
  const size_t HB_OFF   = XG_OFF + XG_SZ;
  const size_t HB_SZ    = (size_t)NROWS * DFF * 2;              // 23.07 MB
  const size_t W_SZ     = (size_t)NW_ELEM * 2;                  // 46.14 MB each
  const size_t GB_OFF   = HB_OFF + HB_SZ;
  const size_t UB_OFF   = GB_OFF + W_SZ;
  const size_t DB_OFF   = UB_OFF + W_SZ;
  const size_t YB_OFF   = DB_OFF + W_SZ;
  const size_t YB_SZ    = (size_t)SLICES_B * NROWS * D_DIM * 4; // 67.1 MB

  unsigned short* xg   = (unsigned short*)(ws + XG_OFF);
  unsigned short* hbuf = (unsigned short*)(ws + HB_OFF);
  unsigned short* gbuf = (unsigned short*)(ws + GB_OFF);
  unsigned short* ubuf = (unsigned short*)(ws + UB_OFF);
  unsigned short* dbuf = (unsigned short*)(ws + DB_OFF);
  float* ybuf = (float*)(ws + YB_OFF);

  routing_kernel<<<1, 512, 0, stream>>>(ids, topk_w, cnt, off, tok, wgt, rowmap);
  gather_x_kernel<<<NROWS, 256, 0, stream>>>(x, tok, xg);

  if (ws_size >= YB_OFF + YB_SZ) {
    // full path: bf16 weights + ybuf split-K
    wconv_kernel<<<2048, 256, 0, stream>>>(gate_w, up_w, down_w, gbuf, ubuf, dbuf);
    moe_gateup_bf<<<NWG_A, 256, 0, stream>>>(gbuf, ubuf, xg, wgt, cnt, off, hbuf);
    moe_down_bf<true><<<NT_B * MT_B * NEXP * SLICES_B, 256, 0, stream>>>(dbuf, hbuf, tok, cnt, off, ybuf);
    combine_kernel<<<T_TOK, 256, 0, stream>>>(ybuf, rowmap, out);
  } else if (ws_size >= YB_OFF) {
    // bf16 weights, atomic down
    wconv_kernel<<<2048, 256, 0, stream>>>(gate_w, up_w, down_w, gbuf, ubuf, dbuf);
    moe_gateup_bf<<<NWG_A, 256, 0, stream>>>(gbuf, ubuf, xg, wgt, cnt, off, hbuf);
    hipMemsetAsync(d_out, 0, (size_t)out_size * sizeof(float), stream);
    moe_down_bf<false><<<NT_B * MT_B * NEXP * SLICES_B, 256, 0, stream>>>(dbuf, hbuf, tok, cnt, off, out);
  } else {
    // round-6 fallback: f32 weights reg-staged
    moe_gateup_f32<<<NWG_A, 256, 0, stream>>>(gate_w, up_w, xg, wgt, cnt, off, hbuf);
    hipMemsetAsync(d_out, 0, (size_t)out_size * sizeof(float), stream);
    moe_down_f32<<<(D_DIM / 64) * (NROWS / 128) * NEXP * 2, 256, 0, stream>>>(down_w, hbuf, tok, cnt, off, out);
  }
}

// Round 8
// 286.442 us; speedup vs baseline: 1.1489x; 1.1489x over previous
//
#include <hip/hip_runtime.h>
#include <stdint.h>

typedef __attribute__((ext_vector_type(8))) __bf16 bf16x8;
typedef __attribute__((ext_vector_type(4))) float f32x4;
typedef __attribute__((ext_vector_type(8))) unsigned short ushort8;

#define T_TOK 2048
#define D_DIM 1024
#define DFF   2816
#define NEXP  8
#define NROWS 4096
#define BK    32
#define NW_ELEM (NEXP * DFF * D_DIM)   // 23,068,672 elems per weight tensor
#define MAXTM 40                        // max m-tiles (BM=128) across experts

// granule swizzle for bf16 tiles (4 x 16B granules per 64B row); involution.
#define SWZ(r,g) ((g) ^ (((r) >> 1) & 3))

// tile list layout (ints, in ws): [0]=ntm; [16+i]=row_base; [80+i]=valid; [144+i]=expert
#define TL_N    0
#define TL_BASE 16
#define TL_VAL  80
#define TL_EXP  144

// ---------- helpers ----------
__device__ __forceinline__ void lds_cp16(const void* g, void* l) {
  __builtin_amdgcn_global_load_lds(
      (const __attribute__((address_space(1))) void*)g,
      (__attribute__((address_space(3))) void*)l, 16, 0, 0);
}

__device__ __forceinline__ ushort8 pack_bf16x8(float4 a, float4 b) {
  union { __bf16 h[8]; ushort8 u; } r;
  r.h[0] = (__bf16)a.x; r.h[1] = (__bf16)a.y; r.h[2] = (__bf16)a.z; r.h[3] = (__bf16)a.w;
  r.h[4] = (__bf16)b.x; r.h[5] = (__bf16)b.y; r.h[6] = (__bf16)b.z; r.h[7] = (__bf16)b.w;
  return r.u;
}

__device__ __forceinline__ unsigned short f2bf(float f) {
  union { __bf16 h; unsigned short u; } r;
  r.h = (__bf16)f;
  return r.u;
}

// ---------- 1. routing + tile-list ----------
__global__ __launch_bounds__(512) void routing_kernel(
    const int* __restrict__ ids, const float* __restrict__ w,
    int* __restrict__ cnt, int* __restrict__ off,
    int* __restrict__ tok, float* __restrict__ wgt, int* __restrict__ rowmap,
    int* __restrict__ tl)
{
  __shared__ int s_cnt[NEXP];
  __shared__ int s_off[NEXP];
  const int lane = threadIdx.x & 63;
  const int e    = threadIdx.x >> 6;

  int total = 0;
  for (int c = 0; c < NROWS / 64; ++c) {
    int id = ids[c * 64 + lane];
    unsigned long long b = __ballot(id == e);
    total += __popcll(b);
  }
  if (lane == 0) s_cnt[e] = total;
  __syncthreads();
  if (threadIdx.x == 0) {
    int acc = 0, nt = 0;
    for (int i = 0; i < NEXP; ++i) {
      s_off[i] = acc; off[i] = acc; cnt[i] = s_cnt[i];
      for (int j = 0; j < s_cnt[i]; j += 128) {
        tl[TL_BASE + nt] = acc + j;
        tl[TL_VAL  + nt] = min(128, s_cnt[i] - j);
        tl[TL_EXP  + nt] = i;
        ++nt;
      }
      acc += s_cnt[i];
    }
    tl[TL_N] = nt;
  }
  __syncthreads();
  int base = s_off[e];
  for (int c = 0; c < NROWS / 64; ++c) {
    int idx = c * 64 + lane;
    int id = ids[idx];
    bool m = (id == e);
    unsigned long long b = __ballot(m);
    int pos = __popcll(b & ((1ull << lane) - 1ull));
    if (m) {
      tok[base + pos] = idx >> 1;
      wgt[base + pos] = w[idx];
      rowmap[idx] = base + pos;
    }
    base += __popcll(b);
  }
}

// ---------- 2. gather x -> bf16 compacted ----------
__global__ __launch_bounds__(256) void gather_x_kernel(
    const float* __restrict__ x, const int* __restrict__ tok,
    unsigned short* __restrict__ xg)
{
  const int i = blockIdx.x;
  const int t = tok[i];
  const float4 v = ((const float4*)(x + (size_t)t * D_DIM))[threadIdx.x];
  ushort4 o;
  o.x = f2bf(v.x); o.y = f2bf(v.y); o.z = f2bf(v.z); o.w = f2bf(v.w);
  ((ushort4*)(xg + (size_t)i * D_DIM))[threadIdx.x] = o;
}

// ---------- 2b. weight conversion gate+up f32 -> bf16 ----------
__global__ __launch_bounds__(256) void wconv_gu_kernel(
    const float* __restrict__ gw, const float* __restrict__ uw,
    unsigned short* __restrict__ gb, unsigned short* __restrict__ ub)
{
  const size_t n = NW_ELEM / 8;
  const size_t stride = (size_t)gridDim.x * blockDim.x;
  for (size_t i = (size_t)blockIdx.x * blockDim.x + threadIdx.x;
       i < 2 * n; i += stride) {
    const bool up = (i >= n);
    const size_t idx = (up ? i - n : i) * 8;
    const float* src = up ? uw : gw;
    unsigned short* dst = up ? ub : gb;
    float4 a = *(const float4*)(src + idx);
    float4 b = *(const float4*)(src + idx + 4);
    *(ushort8*)(dst + idx) = pack_bf16x8(a, b);
  }
}

// ---------- 3. grouped GEMM (compact work list) + fused down-weight conv ----------
#define BM_A 128
#define BN_A 64
#define NT_A (DFF / BN_A)            // 44
#define NWORK_A_MAX (MAXTM * NT_A)   // 1760
#define WCD_BLKS 2048
#define NWG_A (NWORK_A_MAX + WCD_BLKS)
#define KT_A (D_DIM / BK)            // 32

__global__ __launch_bounds__(256) void moe_gateup_bf(
    const unsigned short* __restrict__ gbuf, const unsigned short* __restrict__ ubuf,
    const unsigned short* __restrict__ xg, const float* __restrict__ wgt,
    const int* __restrict__ tl,
    unsigned short* __restrict__ hbuf,
    const float* __restrict__ down_w, unsigned short* __restrict__ dbuf)
{
  const int bid = blockIdx.x;
  const int ntm = tl[TL_N];
  const int nwork = ntm * NT_A;
  if (bid >= nwork) {
    if (bid >= NWORK_A_MAX) {
      // fused down-weight conversion (streams at idle HBM BW during GEMM)
      const int c = bid - NWORK_A_MAX;
      const size_t stride = (size_t)WCD_BLKS * 256;
      for (size_t i = (size_t)c * 256 + threadIdx.x; i < NW_ELEM / 8; i += stride) {
        const size_t idx = i * 8;
        float4 a = *(const float4*)(down_w + idx);
        float4 b = *(const float4*)(down_w + idx + 4);
        *(ushort8*)(dbuf + idx) = pack_bf16x8(a, b);
      }
    }
    return;
  }
  const int tile = bid % ntm;
  const int nt   = bid / ntm;
  const int row_base = tl[TL_BASE + tile];
  const int valid    = tl[TL_VAL  + tile];
  const int e        = tl[TL_EXP  + tile];
  const int n0 = nt * BN_A;

  __shared__ __align__(16) unsigned short Alds[2][BM_A * BK]; // 2 x 8KB
  __shared__ __align__(16) unsigned short Bg[2][BN_A * BK];   // 2 x 4KB
  __shared__ __align__(16) unsigned short Bu[2][BN_A * BK];   // 2 x 4KB

  const int tid = threadIdx.x;
  const int lane = tid & 63;
  const int wid = tid >> 6;
  const int wm = wid >> 1, wn = wid & 1;   // wave subtile 64x32
  const int lhi = lane >> 4, llo = lane & 15;

  f32x4 accg[4][2], accu[4][2];
  #pragma unroll
  for (int i = 0; i < 4; ++i)
    #pragma unroll
    for (int j = 0; j < 2; ++j) {
      accg[i][j] = (f32x4){0.f, 0.f, 0.f, 0.f};
      accu[i][j] = (f32x4){0.f, 0.f, 0.f, 0.f};
    }

  const unsigned short* gb = gbuf + ((size_t)e * DFF + n0) * D_DIM;
  const unsigned short* ub = ubuf + ((size_t)e * DFF + n0) * D_DIM;

  const int ar0 = tid >> 2,          ag0 = tid & 3;
  const int ar1 = (tid + 256) >> 2,  ag1 = tid & 3;
  const size_t a_src0 = (size_t)(row_base + min(ar0, valid - 1)) * D_DIM + SWZ(ar0, ag0) * 8;
  const size_t a_src1 = (size_t)(row_base + min(ar1, valid - 1)) * D_DIM + SWZ(ar1, ag1) * 8;
  const int br = tid >> 2, bg = tid & 3;
  const size_t b_src = (size_t)br * D_DIM + SWZ(br, bg) * 8;

  lds_cp16(xg + a_src0, &Alds[0][tid * 8]);
  lds_cp16(xg + a_src1, &Alds[0][(tid + 256) * 8]);
  lds_cp16(gb + b_src, &Bg[0][tid * 8]);
  lds_cp16(ub + b_src, &Bu[0][tid * 8]);
  __syncthreads();

  for (int t = 0; t < KT_A; ++t) {
    const int cur = t & 1, nxt = cur ^ 1;
    const int kn = (t + 1 < KT_A) ? (t + 1) * BK : 0;

    lds_cp16(xg + a_src0 + kn, &Alds[nxt][tid * 8]);
    lds_cp16(xg + a_src1 + kn, &Alds[nxt][(tid + 256) * 8]);
    lds_cp16(gb + b_src + kn, &Bg[nxt][tid * 8]);
    lds_cp16(ub + b_src + kn, &Bu[nxt][tid * 8]);

    bf16x8 a[4], bgf[2], buf_[2];
    #pragma unroll
    for (int mi = 0; mi < 4; ++mi) {
      int row = wm * 64 + mi * 16 + llo;
      a[mi] = *(const bf16x8*)&Alds[cur][row * BK + SWZ(row, lhi) * 8];
    }
    #pragma unroll
    for (int ni = 0; ni < 2; ++ni) {
      int row = wn * 32 + ni * 16 + llo;
      bgf[ni]  = *(const bf16x8*)&Bg[cur][row * BK + SWZ(row, lhi) * 8];
      buf_[ni] = *(const bf16x8*)&Bu[cur][row * BK + SWZ(row, lhi) * 8];
    }
    #pragma unroll
    for (int mi = 0; mi < 4; ++mi)
      #pragma unroll
      for (int ni = 0; ni < 2; ++ni) {
        accg[mi][ni] = __builtin_amdgcn_mfma_f32_16x16x32_bf16(a[mi], bgf[ni], accg[mi][ni], 0, 0, 0);
        accu[mi][ni] = __builtin_amdgcn_mfma_f32_16x16x32_bf16(a[mi], buf_[ni], accu[mi][ni], 0, 0, 0);
      }
    __syncthreads();
  }

  // epilogue: h = silu(g)*u*w -> bf16
  #pragma unroll
  for (int mi = 0; mi < 4; ++mi) {
    #pragma unroll
    for (int r = 0; r < 4; ++r) {
      int row = wm * 64 + mi * 16 + lhi * 4 + r;
      if (row < valid) {
        int grow = row_base + row;
        float wv = wgt[grow];
        size_t base = (size_t)grow * DFF + n0 + wn * 32;
        #pragma unroll
        for (int ni = 0; ni < 2; ++ni) {
          float g = accg[mi][ni][r];
          float u = accu[mi][ni][r];
          float h = (g / (1.f + __expf(-g))) * u * wv;
          hbuf[base + ni * 16 + llo] = f2bf(h);
        }
      }
    }
  }
}

// ---------- 4. grouped GEMM (compact, split-K): y = h downT ----------
#define BM_B 128
#define BN_B 128
#define NT_B (D_DIM / BN_B)     // 8
#define SLICES_B 4
#define NWG_B (MAXTM * NT_B * SLICES_B)  // 1280

template <bool USE_YBUF>
__global__ __launch_bounds__(256) void moe_down_bf(
    const unsigned short* __restrict__ dbuf,
    const unsigned short* __restrict__ hbuf,
    const int* __restrict__ tok,
    const int* __restrict__ tl,
    float* __restrict__ ybuf_or_out)
{
  constexpr int KS = DFF / SLICES_B;   // 704
  constexpr int KT = KS / BK;          // 22

  const int bid = blockIdx.x;
  const int ntm = tl[TL_N];
  const int nwork = ntm * NT_B * SLICES_B;
  if (bid >= nwork) return;
  const int tile = bid % ntm;
  const int r1_  = bid / ntm;
  const int nt = r1_ % NT_B;
  const int sl = r1_ / NT_B;
  const int row_base = tl[TL_BASE + tile];
  const int valid    = tl[TL_VAL  + tile];
  const int e        = tl[TL_EXP  + tile];
  const int n0 = nt * BN_B;
  const int kbeg = sl * KS;

  __shared__ __align__(16) unsigned short Alds[2][BM_B * BK]; // 2 x 8KB
  __shared__ __align__(16) unsigned short Blds[2][BN_B * BK]; // 2 x 8KB

  const int tid = threadIdx.x, lane = tid & 63, wid = tid >> 6;
  const int wm = wid >> 1, wn = wid & 1;   // wave subtile 64x64
  const int lhi = lane >> 4, llo = lane & 15;

  f32x4 acc[4][4];
  #pragma unroll
  for (int i = 0; i < 4; ++i)
    #pragma unroll
    for (int j = 0; j < 4; ++j) acc[i][j] = (f32x4){0.f, 0.f, 0.f, 0.f};

  const unsigned short* db = dbuf + ((size_t)e * D_DIM + n0) * DFF;

  const int ar0 = tid >> 2,          ag0 = tid & 3;
  const int ar1 = (tid + 256) >> 2,  ag1 = tid & 3;
  const size_t a_src0 = (size_t)(row_base + min(ar0, valid - 1)) * DFF + SWZ(ar0, ag0) * 8;
  const size_t a_src1 = (size_t)(row_base + min(ar1, valid - 1)) * DFF + SWZ(ar1, ag1) * 8;
  const size_t b_src0 = (size_t)ar0 * DFF + SWZ(ar0, ag0) * 8;
  const size_t b_src1 = (size_t)ar1 * DFF + SWZ(ar1, ag1) * 8;

  lds_cp16(hbuf + a_src0 + kbeg, &Alds[0][tid * 8]);
  lds_cp16(hbuf + a_src1 + kbeg, &Alds[0][(tid + 256) * 8]);
  lds_cp16(db + b_src0 + kbeg, &Blds[0][tid * 8]);
  lds_cp16(db + b_src1 + kbeg, &Blds[0][(tid + 256) * 8]);
  __syncthreads();

  for (int t = 0; t < KT; ++t) {
    const int cur = t & 1, nxt = cur ^ 1;
    const int kn = kbeg + ((t + 1 < KT) ? (t + 1) * BK : 0);

    lds_cp16(hbuf + a_src0 + kn, &Alds[nxt][tid * 8]);
    lds_cp16(hbuf + a_src1 + kn, &Alds[nxt][(tid + 256) * 8]);
    lds_cp16(db + b_src0 + kn, &Blds[nxt][tid * 8]);
    lds_cp16(db + b_src1 + kn, &Blds[nxt][(tid + 256) * 8]);

    bf16x8 a[4], b[4];
    #pragma unroll
    for (int mi = 0; mi < 4; ++mi) {
      int row = wm * 64 + mi * 16 + llo;
      a[mi] = *(const bf16x8*)&Alds[cur][row * BK + SWZ(row, lhi) * 8];
    }
    #pragma unroll
    for (int ni = 0; ni < 4; ++ni) {
      int row = wn * 64 + ni * 16 + llo;
      b[ni] = *(const bf16x8*)&Blds[cur][row * BK + SWZ(row, lhi) * 8];
    }
    #pragma unroll
    for (int mi = 0; mi < 4; ++mi)
      #pragma unroll
      for (int ni = 0; ni < 4; ++ni)
        acc[mi][ni] = __builtin_amdgcn_mfma_f32_16x16x32_bf16(a[mi], b[ni], acc[mi][ni], 0, 0, 0);
    __syncthreads();
  }

  #pragma unroll
  for (int mi = 0; mi < 4; ++mi) {
    #pragma unroll
    for (int r = 0; r < 4; ++r) {
      int row = wm * 64 + mi * 16 + lhi * 4 + r;
      if (row < valid) {
        if (USE_YBUF) {
          float* yp = ybuf_or_out + ((size_t)sl * NROWS + row_base + row) * D_DIM + n0 + wn * 64;
          #pragma unroll
          for (int ni = 0; ni < 4; ++ni) yp[ni * 16 + llo] = acc[mi][ni][r];
        } else {
          int tk = tok[row_base + row];
          float* op = ybuf_or_out + (size_t)tk * D_DIM + n0 + wn * 64;
          #pragma unroll
          for (int ni = 0; ni < 4; ++ni) atomicAdd(op + ni * 16 + llo, acc[mi][ni][r]);
        }
      }
    }
  }
}

// ---------- fallback (f32 weights reg-staged; round-6 proven path) ----------
#define MT_F (NROWS / BM_A)
#define NWGF_A (NT_A * MT_F * NEXP)

__global__ __launch_bounds__(256) void moe_gateup_f32(
    const float* __restrict__ gate_w, const float* __restrict__ up_w,
    const unsigned short* __restrict__ xg, const float* __restrict__ wgt,
    const int* __restrict__ cnt, const int* __restrict__ off,
    unsigned short* __restrict__ hbuf)
{
  const int orig = blockIdx.x;
  const int wgid = (orig & 7) * (NWGF_A >> 3) + (orig >> 3);
  const int mt = wgid % MT_F;
  const int t1 = wgid / MT_F;
  const int nt = t1 % NT_A;
  const int e  = t1 / NT_A;

  const int cnte = cnt[e];
  const int m0 = mt * BM_A;
  if (m0 >= cnte) return;
  const int row_base = off[e] + m0;
  const int valid = min(BM_A, cnte - m0);
  const int n0 = nt * BN_A;

  __shared__ __align__(16) unsigned short Alds[2][BM_A * BK];
  __shared__ __align__(16) unsigned short Bg[2][BN_A * BK];
  __shared__ __align__(16) unsigned short Bu[2][BN_A * BK];

  const int tid = threadIdx.x;
  const int lane = tid & 63;
  const int wid = tid >> 6;
  const int wm = wid >> 1, wn = wid & 1;
  const int lhi = lane >> 4, llo = lane & 15;

  f32x4 accg[4][2], accu[4][2];
  #pragma unroll
  for (int i = 0; i < 4; ++i)
    #pragma unroll
    for (int j = 0; j < 2; ++j) {
      accg[i][j] = (f32x4){0.f, 0.f, 0.f, 0.f};
      accu[i][j] = (f32x4){0.f, 0.f, 0.f, 0.f};
    }

  const float* gbase = gate_w + ((size_t)e * DFF + n0) * D_DIM;
  const float* ubase = up_w   + ((size_t)e * DFF + n0) * D_DIM;
  const int rowb = tid >> 2;
  const int gidx = tid & 3;

  const int ar0 = tid >> 2,          ag0 = tid & 3;
  const int ar1 = (tid + 256) >> 2,  ag1 = tid & 3;
  const size_t a_src0 = (size_t)(row_base + min(ar0, valid - 1)) * D_DIM + SWZ(ar0, ag0) * 8;
  const size_t a_src1 = (size_t)(row_base + min(ar1, valid - 1)) * D_DIM + SWZ(ar1, ag1) * 8;
  const size_t boff  = (size_t)rowb * D_DIM + gidx * 8;
  const int bws = rowb * BK + SWZ(rowb, gidx) * 8;

  lds_cp16(xg + a_src0, &Alds[0][tid * 8]);
  lds_cp16(xg + a_src1, &Alds[0][(tid + 256) * 8]);
  {
    const float* gp = gbase + boff;
    const float* up = ubase + boff;
    *(ushort8*)&Bg[0][bws] = pack_bf16x8(*(const float4*)gp, *(const float4*)(gp + 4));
    *(ushort8*)&Bu[0][bws] = pack_bf16x8(*(const float4*)up, *(const float4*)(up + 4));
  }
  float4 pg0, pg1, pu0, pu1;
  {
    const float* gp = gbase + boff + BK;
    const float* up = ubase + boff + BK;
    pg0 = *(const float4*)gp; pg1 = *(const float4*)(gp + 4);
    pu0 = *(const float4*)up; pu1 = *(const float4*)(up + 4);
  }
  __syncthreads();

  for (int t = 0; t < KT_A; ++t) {
    const int cur = t & 1, nxt = cur ^ 1;
    const int kn1 = (t + 1 < KT_A) ? (t + 1) * BK : 0;
    const int kn2 = (t + 2 < KT_A) ? (t + 2) * BK : 0;

    lds_cp16(xg + a_src0 + kn1, &Alds[nxt][tid * 8]);
    lds_cp16(xg + a_src1 + kn1, &Alds[nxt][(tid + 256) * 8]);
    const float* gp = gbase + boff + kn2;
    const float* up = ubase + boff + kn2;
    float4 ng0 = *(const float4*)gp, ng1 = *(const float4*)(gp + 4);
    float4 nu0 = *(const float4*)up, nu1 = *(const float4*)(up + 4);
    *(ushort8*)&Bg[nxt][bws] = pack_bf16x8(pg0, pg1);
    *(ushort8*)&Bu[nxt][bws] = pack_bf16x8(pu0, pu1);

    bf16x8 a[4], bgf[2], buf_[2];
    #pragma unroll
    for (int mi = 0; mi < 4; ++mi) {
      int row = wm * 64 + mi * 16 + llo;
      a[mi] = *(const bf16x8*)&Alds[cur][row * BK + SWZ(row, lhi) * 8];
    }
    #pragma unroll
    for (int ni = 0; ni < 2; ++ni) {
      int row = wn * 32 + ni * 16 + llo;
      bgf[ni]  = *(const bf16x8*)&Bg[cur][row * BK + SWZ(row, lhi) * 8];
      buf_[ni] = *(const bf16x8*)&Bu[cur][row * BK + SWZ(row, lhi) * 8];
    }
    #pragma unroll
    for (int mi = 0; mi < 4; ++mi)
      #pragma unroll
      for (int ni = 0; ni < 2; ++ni) {
        accg[mi][ni] = __builtin_amdgcn_mfma_f32_16x16x32_bf16(a[mi], bgf[ni], accg[mi][ni], 0, 0, 0);
        accu[mi][ni] = __builtin_amdgcn_mfma_f32_16x16x32_bf16(a[mi], buf_[ni], accu[mi][ni], 0, 0, 0);
      }

    pg0 = ng0; pg1 = ng1; pu0 = nu0; pu1 = nu1;
    __syncthreads();
  }

  #pragma unroll
  for (int mi = 0; mi < 4; ++mi) {
    #pragma unroll
    for (int r = 0; r < 4; ++r) {
      int row = wm * 64 + mi * 16 + lhi * 4 + r;
      if (row < valid) {
        int grow = row_base + row;
        float wv = wgt[grow];
        size_t base = (size_t)grow * DFF + n0 + wn * 32;
        #pragma unroll
        for (int ni = 0; ni < 2; ++ni) {
          float g = accg[mi][ni][r];
          float u = accu[mi][ni][r];
          float h = (g / (1.f + __expf(-g))) * u * wv;
          hbuf[base + ni * 16 + llo] = f2bf(h);
        }
      }
    }
  }
}

__global__ __launch_bounds__(256) void moe_down_f32(
    const float* __restrict__ down_w,
    const unsigned short* __restrict__ hbuf,
    const int* __restrict__ tok,
    const int* __restrict__ cnt, const int* __restrict__ off,
    float* __restrict__ out)
{
  constexpr int SLICES = 2;
  constexpr int KS = DFF / SLICES;
  constexpr int KT = KS / BK;
  constexpr int BMf = 128, BNf = 64;
  constexpr int NTf = D_DIM / BNf, MTf = NROWS / BMf;
  constexpr int NWG = NTf * MTf * NEXP * SLICES;

  const int orig = blockIdx.x;
  const int wgid = (orig & 7) * (NWG >> 3) + (orig >> 3);
  const int mt = wgid % MTf;
  const int t1 = wgid / MTf;
  const int nt = t1 % NTf;
  const int t2 = t1 / NTf;
  const int e  = t2 % NEXP;
  const int sl = t2 / NEXP;

  const int cnte = cnt[e];
  const int m0 = mt * BMf;
  if (m0 >= cnte) return;
  const int row_base = off[e] + m0;
  const int valid = min(BMf, cnte - m0);
  const int n0 = nt * BNf;
  const int kbeg = sl * KS;

  __shared__ __align__(16) unsigned short Alds[2][BMf * BK];
  __shared__ __align__(16) unsigned short Blds[2][BNf * BK];

  const int tid = threadIdx.x, lane = tid & 63, wid = tid >> 6;
  const int wm = wid >> 1, wn = wid & 1;
  const int lhi = lane >> 4, llo = lane & 15;

  f32x4 acc[4][2];
  #pragma unroll
  for (int i = 0; i < 4; ++i)
    #pragma unroll
    for (int j = 0; j < 2; ++j) acc[i][j] = (f32x4){0.f, 0.f, 0.f, 0.f};

  const float* dbase = down_w + ((size_t)e * D_DIM + n0) * DFF;
  const int rowb = tid >> 2, gidx = tid & 3;
  const int ar0 = tid >> 2,          ag0 = tid & 3;
  const int ar1 = (tid + 256) >> 2,  ag1 = tid & 3;
  const size_t a_src0 = (size_t)(row_base + min(ar0, valid - 1)) * DFF + SWZ(ar0, ag0) * 8;
  const size_t a_src1 = (size_t)(row_base + min(ar1, valid - 1)) * DFF + SWZ(ar1, ag1) * 8;
  const size_t boff  = (size_t)rowb * DFF + gidx * 8;
  const int bws = rowb * BK + SWZ(rowb, gidx) * 8;

  lds_cp16(hbuf + a_src0 + kbeg, &Alds[0][tid * 8]);
  lds_cp16(hbuf + a_src1 + kbeg, &Alds[0][(tid + 256) * 8]);
  {
    const float* dp = dbase + boff + kbeg;
    *(ushort8*)&Blds[0][bws] = pack_bf16x8(*(const float4*)dp, *(const float4*)(dp + 4));
  }
  float4 pd0, pd1;
  {
    const float* dp = dbase + boff + kbeg + BK;
    pd0 = *(const float4*)dp; pd1 = *(const float4*)(dp + 4);
  }
  __syncthreads();

  for (int t = 0; t < KT; ++t) {
    const int cur = t & 1, nxt = cur ^ 1;
    const int kn1 = kbeg + ((t + 1 < KT) ? (t + 1) * BK : 0);
    const int kn2 = kbeg + ((t + 2 < KT) ? (t + 2) * BK : 0);

    lds_cp16(hbuf + a_src0 + kn1, &Alds[nxt][tid * 8]);
    lds_cp16(hbuf + a_src1 + kn1, &Alds[nxt][(tid + 256) * 8]);
    const float* dp = dbase + boff + kn2;
    float4 nd0 = *(const float4*)dp, nd1 = *(const float4*)(dp + 4);
    *(ushort8*)&Blds[nxt][bws] = pack_bf16x8(pd0, pd1);

    bf16x8 a[4], b[2];
    #pragma unroll
    for (int mi = 0; mi < 4; ++mi) {
      int row = wm * 64 + mi * 16 + llo;
      a[mi] = *(const bf16x8*)&Alds[cur][row * BK + SWZ(row, lhi) * 8];
    }
    #pragma unroll
    for (int ni = 0; ni < 2; ++ni) {
      int row = wn * 32 + ni * 16 + llo;
      b[ni] = *(const bf16x8*)&Blds[cur][row * BK + SWZ(row, lhi) * 8];
    }
    #pragma unroll
    for (int mi = 0; mi < 4; ++mi)
      #pragma unroll
      for (int ni = 0; ni < 2; ++ni)
        acc[mi][ni] = __builtin_amdgcn_mfma_f32_16x16x32_bf16(a[mi], b[ni], acc[mi][ni], 0, 0, 0);

    pd0 = nd0; pd1 = nd1;
    __syncthreads();
  }

  #pragma unroll
  for (int mi = 0; mi < 4; ++mi) {
    #pragma unroll
    for (int r = 0; r < 4; ++r) {
      int row = wm * 64 + mi * 16 + lhi * 4 + r;
      if (row < valid) {
        int tk = tok[row_base + row];
        float* op = out + (size_t)tk * D_DIM + n0 + wn * 32;
        #pragma unroll
        for (int ni = 0; ni < 2; ++ni) atomicAdd(op + ni * 16 + llo, acc[mi][ni][r]);
      }
    }
  }
}

// ---------- 5. combine ----------
__global__ __launch_bounds__(256) void combine_kernel(
    const float* __restrict__ ybuf, const int* __restrict__ rowmap,
    float* __restrict__ out)
{
  const int t = blockIdx.x;
  const int d = threadIdx.x * 4;
  const int r0 = rowmap[t * 2], r1 = rowmap[t * 2 + 1];
  float4 s = {0.f, 0.f, 0.f, 0.f};
  #pragma unroll
  for (int sl = 0; sl < SLICES_B; ++sl) {
    const float4 a = *(const float4*)(ybuf + ((size_t)sl * NROWS + r0) * D_DIM + d);
    const float4 b = *(const float4*)(ybuf + ((size_t)sl * NROWS + r1) * D_DIM + d);
    s.x += a.x + b.x; s.y += a.y + b.y; s.z += a.z + b.z; s.w += a.w + b.w;
  }
  *(float4*)(out + (size_t)t * D_DIM + d) = s;
}

// ---------- launch ----------
extern "C" void kernel_launch(void* const* d_in, const int* in_sizes, int n_in,
                              void* d_out, int out_size, void* d_ws, size_t ws_size,
                              hipStream_t stream) {
  const float* x      = (const float*)d_in[0];
  const float* topk_w = (const float*)d_in[1];
  const float* gate_w = (const float*)d_in[2];
  const float* up_w   = (const float*)d_in[3];
  const float* down_w = (const float*)d_in[4];
  const int*   ids    = (const int*)d_in[5];
  float* out = (float*)d_out;

  char* ws = (char*)d_ws;
  int*   cnt    = (int*)(ws + 0);
  int*   off    = (int*)(ws + 32);
  int*   tok    = (int*)(ws + 64);
  float* wgt    = (float*)(ws + 64 + NROWS * 4);
  int*   rowmap = (int*)(ws + 64 + NROWS * 8);
  int*   tl     = (int*)(ws + 49664);   // 4 + 3*64 ints

  const size_t XG_OFF   = 65536;
  const size_t XG_SZ    = (size_t)NROWS * D_DIM * 2;            // 8 MB
  const size_t HB_OFF   = XG_OFF + XG_SZ;
  const size_t HB_SZ    = (size_t)NROWS * DFF * 2;              // 23.07 MB
  const size_t W_SZ     = (size_t)NW_ELEM * 2;                  // 46.14 MB each
  const size_t GB_OFF   = HB_OFF + HB_SZ;
  const size_t UB_OFF   = GB_OFF + W_SZ;
  const size_t DB_OFF   = UB_OFF + W_SZ;
  const size_t YB_OFF   = DB_OFF + W_SZ;
  const size_t YB_SZ    = (size_t)SLICES_B * NROWS * D_DIM * 4; // 67.1 MB

  unsigned short* xg   = (unsigned short*)(ws + XG_OFF);
  unsigned short* hbuf = (unsigned short*)(ws + HB_OFF);
  unsigned short* gbuf = (unsigned short*)(ws + GB_OFF);
  unsigned short* ubuf = (unsigned short*)(ws + UB_OFF);
  unsigned short* dbuf = (unsigned short*)(ws + DB_OFF);
  float* ybuf = (float*)(ws + YB_OFF);

  routing_kernel<<<1, 512, 0, stream>>>(ids, topk_w, cnt, off, tok, wgt, rowmap, tl);
  gather_x_kernel<<<NROWS, 256, 0, stream>>>(x, tok, xg);

  if (ws_size >= YB_OFF + YB_SZ) {
    wconv_gu_kernel<<<4096, 256, 0, stream>>>(gate_w, up_w, gbuf, ubuf);
    moe_gateup_bf<<<NWG_A, 256, 0, stream>>>(gbuf, ubuf, xg, wgt, tl, hbuf, down_w, dbuf);
    moe_down_bf<true><<<NWG_B, 256, 0, stream>>>(dbuf, hbuf, tok, tl, ybuf);
    combine_kernel<<<T_TOK, 256, 0, stream>>>(ybuf, rowmap, out);
  } else if (ws_size >= YB_OFF) {
    wconv_gu_kernel<<<4096, 256, 0, stream>>>(gate_w, up_w, gbuf, ubuf);
    moe_gateup_bf<<<NWG_A, 256, 0, stream>>>(gbuf, ubuf, xg, wgt, tl, hbuf, down_w, dbuf);
    hipMemsetAsync(d_out, 0, (size_t)out_size * sizeof(float), stream);
    moe_down_bf<false><<<NWG_B, 256, 0, stream>>>(dbuf, hbuf, tok, tl, out);
  } else {
    moe_gateup_f32<<<NWGF_A, 256, 0, stream>>>(gate_w, up_w, xg, wgt, cnt, off, hbuf);
    hipMemsetAsync(d_out, 0, (size_t)out_size * sizeof(float), stream);
    moe_down_f32<<<(D_DIM / 64) * (NROWS / 128) * NEXP * 2, 256, 0, stream>>>(down_w, hbuf, tok, cnt, off, out);
  }
}